// Round 1
// baseline (484.940 us; speedup 1.0000x reference)
//
#include <hip/hip_runtime.h>
#include <hip/hip_bf16.h>
#include <cmath>

#define BATCH     16384
#define CTX       10
#define NSENSE    8
#define VEC_DIM   128
#define XCOLS     (2 + CTX)

// One wave (64 lanes) per batch element. Lane l owns dims {2l, 2l+1} (float2).
// Row reads are 64 lanes x 8 B = 512 B fully coalesced.
__global__ __launch_bounds__(256) void SenseEmbedding_40295383171457_kernel(
    const int*   __restrict__ x,     // [BATCH, 12]
    const float* __restrict__ Wg,    // [VOCAB, 128]
    const float* __restrict__ Ws,    // [VOCAB, 8, 128]
    float*       __restrict__ out)   // [BATCH, 1]
{
    const int wave = (blockIdx.x * blockDim.x + threadIdx.x) >> 6;
    const int lane = threadIdx.x & 63;
    if (wave >= BATCH) return;

    const int* xr = x + wave * XCOLS;
    const int w0 = xr[0];
    const int w1 = xr[1];

    // ---- sum_context: sum of 10 gathered W_g rows, 2 dims/lane ----
    float2 csum = make_float2(0.f, 0.f);
    #pragma unroll
    for (int c = 0; c < CTX; ++c) {
        const int idx = xr[2 + c];
        const float2 g = *reinterpret_cast<const float2*>(
            Wg + (size_t)idx * VEC_DIM + 2 * lane);
        csum.x += g.x;
        csum.y += g.y;
    }

    // ---- scores[k] = <W_s[w0,k,:], sum_context> for k=0..7 ----
    const float* srow = Ws + (size_t)w0 * (NSENSE * VEC_DIM);
    float scores[NSENSE];
    #pragma unroll
    for (int k = 0; k < NSENSE; ++k) {
        const float2 s = *reinterpret_cast<const float2*>(
            srow + k * VEC_DIM + 2 * lane);
        float p = s.x * csum.x + s.y * csum.y;
        // butterfly reduction over 64 lanes -> every lane holds the full sum
        #pragma unroll
        for (int off = 32; off > 0; off >>= 1)
            p += __shfl_xor(p, off, 64);
        scores[k] = p;
    }

    // ---- argmax (first-occurrence, matches jnp.argmax) ----
    int   best = 0;
    float bv   = scores[0];
    #pragma unroll
    for (int k = 1; k < NSENSE; ++k) {
        if (scores[k] > bv) { bv = scores[k]; best = k; }
    }

    // ---- dot(chosen, W_g[w1]) ----
    // Re-load chosen sense row (L1-hot; avoids dynamic-indexed reg array).
    const float2 ch = *reinterpret_cast<const float2*>(
        srow + best * VEC_DIM + 2 * lane);
    const float2 tg = *reinterpret_cast<const float2*>(
        Wg + (size_t)w1 * VEC_DIM + 2 * lane);
    float d = ch.x * tg.x + ch.y * tg.y;
    #pragma unroll
    for (int off = 32; off > 0; off >>= 1)
        d += __shfl_xor(d, off, 64);

    if (lane == 0) {
        out[wave] = 1.f / (1.f + expf(-d));
    }
}

extern "C" void kernel_launch(void* const* d_in, const int* in_sizes, int n_in,
                              void* d_out, int out_size, void* d_ws, size_t ws_size,
                              hipStream_t stream) {
    const int*   x  = (const int*)  d_in[0];
    const float* Wg = (const float*)d_in[1];
    const float* Ws = (const float*)d_in[2];
    float*       out = (float*)d_out;

    // 4 waves per 256-thread block, one wave per batch element.
    const int waves_per_block = 256 / 64;
    const int grid = (BATCH + waves_per_block - 1) / waves_per_block;
    SenseEmbedding_40295383171457_kernel<<<grid, 256, 0, stream>>>(x, Wg, Ws, out);
}